// Round 7
// baseline (69.937 us; speedup 1.0000x reference)
//
#include <hip/hip_runtime.h>
#include <math.h>
#include <stdint.h>

#define B_    16
#define CONDC 256
#define ICn   64
#define OCn   64
#define Hn    128
#define Wn    128
#define NW    36864
#define NPARAM 36928

typedef _Float16 half8 __attribute__((ext_vector_type(8)));
typedef _Float16 half4 __attribute__((ext_vector_type(4)));
typedef float f32x4 __attribute__((ext_vector_type(4)));
typedef float f32x16 __attribute__((ext_vector_type(16)));

__device__ inline unsigned pk2(float a, float b) {
    union { _Float16 h[2]; unsigned u; } q;
    q.h[0] = (_Float16)a; q.h[1] = (_Float16)b;
    return q.u;
}

// ===================== TRANSPOSE: x[b][ic][y][:] f32 -> xt[b][y+1][x+1][ic] f16 =====================
// blocks [0,2048): one interior row each; [2048,2080): halo memset. 16.6 KB LDS.
__global__ void transpose_k(const float* __restrict__ x, _Float16* __restrict__ xt) {
    __shared__ unsigned ls[4160];              // [32 icp][130] u32
    const int tid = threadIdx.x;
    const int bx  = blockIdx.x;

    if (bx < 2048) {
        const int b = bx >> 7, y = bx & 127;
        const float* xrow = x + (size_t)b * 1048576 + (size_t)y * 128;

        float4 va[4], vb[4];                   // ALL 8 loads issued, pinned by sched_barrier
        #pragma unroll
        for (int t = 0; t < 4; ++t) {
            int u = t * 256 + tid;
            int icp = u >> 5, xg = u & 31;
            const float* r0 = xrow + (size_t)(2 * icp) * 16384;
            va[t] = *((const float4*)r0 + xg);
            vb[t] = *((const float4*)(r0 + 16384) + xg);
        }
        __builtin_amdgcn_sched_barrier(0);     // loads may NOT sink below this point

        #pragma unroll
        for (int t = 0; t < 4; ++t) {
            int u = t * 256 + tid;
            int icp = u >> 5, xg = u & 31;
            unsigned* dst = ls + icp * 130 + 4 * xg;
            *(uint2*)(dst)     = make_uint2(pk2(va[t].x, vb[t].x), pk2(va[t].y, vb[t].y));
            *(uint2*)(dst + 2) = make_uint2(pk2(va[t].z, vb[t].z), pk2(va[t].w, vb[t].w));
        }
        __syncthreads();

        _Float16* rowhalf = xt + (size_t)(b * 130 + y + 1) * 8320;
        #pragma unroll
        for (int t = 0; t < 5; ++t) {
            int u = t * 256 + tid;
            if (u < 1040) {
                int xp = u >> 3, g = u & 7;
                uint4 val = make_uint4(0u, 0u, 0u, 0u);
                if (xp > 0 && xp < 129) {
                    int xx = xp - 1;
                    val.x = ls[(4 * g + 0) * 130 + xx];
                    val.y = ls[(4 * g + 1) * 130 + xx];
                    val.z = ls[(4 * g + 2) * 130 + xx];
                    val.w = ls[(4 * g + 3) * 130 + xx];
                }
                *(uint4*)(rowhalf + (size_t)u * 8) = val;
            }
        }
    } else {
        const int q = bx - 2048;
        const int b = q >> 1, yp = (q & 1) ? 129 : 0;
        _Float16* rowhalf = xt + (size_t)(b * 130 + yp) * 8320;
        uint4 z = make_uint4(0u, 0u, 0u, 0u);
        for (int u = tid; u < 1040; u += 256)
            *(uint4*)(rowhalf + (size_t)u * 8) = z;
    }
}

// ===================== COND-GEMM: wt[b][icq][tap][oc][ic16] f16 + bias =====================
// 577 blocks x 64 params; Wc staged coalesced, loads pinned-batched.
__global__ __launch_bounds__(256, 4) void gemm_k(const float* __restrict__ cond,
                                                 const float* __restrict__ Wc,
                                                 const float* __restrict__ bc,
                                                 _Float16* __restrict__ wt,
                                                 float* __restrict__ bias) {
    __shared__ _Float16 wl[64 * 280];          // 35840 B
    const int tid = threadIdx.x;
    const int pbase = blockIdx.x * 64;

    float4 v[16];                              // 64 rows x 64 float4, all in flight
    #pragma unroll
    for (int t = 0; t < 16; ++t) {
        int u = t * 256 + tid;
        int pl = u >> 6, kg = u & 63;
        v[t] = *((const float4*)(Wc + (size_t)(pbase + pl) * 256) + kg);
    }
    __builtin_amdgcn_sched_barrier(0);

    #pragma unroll
    for (int t = 0; t < 16; ++t) {
        int u = t * 256 + tid;
        int pl = u >> 6, kg = u & 63;
        half4 h = { (_Float16)v[t].x, (_Float16)v[t].y, (_Float16)v[t].z, (_Float16)v[t].w };
        *(half4*)(wl + pl * 280 + kg * 4) = h;
    }
    __syncthreads();

    const int w = tid >> 6, l = tid & 63, n = l & 15, r4 = l >> 4;
    const _Float16* arow = wl + (w * 16 + n) * 280 + r4 * 8;
    const float*    crow = cond + n * 256 + r4 * 8;
    f32x4 acc = (f32x4){0.f, 0.f, 0.f, 0.f};
    #pragma unroll
    for (int kk = 0; kk < 8; ++kk) {
        half8 av = *(const half8*)(arow + kk * 32);
        float4 u0 = *(const float4*)(crow + kk * 32);
        float4 u1 = *(const float4*)(crow + kk * 32 + 4);
        half8 bv;
        bv[0] = (_Float16)u0.x; bv[1] = (_Float16)u0.y; bv[2] = (_Float16)u0.z; bv[3] = (_Float16)u0.w;
        bv[4] = (_Float16)u1.x; bv[5] = (_Float16)u1.y; bv[6] = (_Float16)u1.z; bv[7] = (_Float16)u1.w;
        acc = __builtin_amdgcn_mfma_f32_16x16x32_f16(av, bv, acc, 0, 0, 0);
    }
    #pragma unroll
    for (int j = 0; j < 4; ++j) {
        int p = pbase + w * 16 + r4 * 4 + j;   // C/D: col=lane&15 (batch), row=(lane>>4)*4+j
        float vv = tanhf(acc[j] + bc[p]) * 5.0f;
        if (p < NW) {
            int oc = p / 576, rem = p - oc * 576;
            int ic = rem / 9,  t  = rem - ic * 9;
            int icq = ic >> 4, icl = ic & 15;
            wt[((((size_t)n * 4 + icq) * 9 + t) * 64 + oc) * 16 + icl] = (_Float16)vv;
        } else {
            bias[n * 64 + (p - NW)] = vv;
        }
    }
}

// ===================== CONV v4 (unchanged): A-in-regs, shared swizzled LDS B, counted vmcnt =====================
__global__ __launch_bounds__(512, 2) void conv_v4(const _Float16* __restrict__ xt,
                                                  const _Float16* __restrict__ wt,
                                                  const float* __restrict__ bias,
                                                  float* __restrict__ out) {
    __shared__ _Float16 xs[2][12288];          // 2 x 24576 B
    const int tid = threadIdx.x;
    const int l   = tid & 63;
    const int w   = tid >> 6;
    const int px  = l & 31;
    const int jj  = l >> 5;
    const int ot  = w & 1;
    const int rg  = w >> 1;
    const int b   = blockIdx.z;
    const int X0  = blockIdx.x * 32;
    const int Y0g = blockIdx.y * 16;

    const _Float16* xbase = xt + ((size_t)(b * 130 + Y0g) * 130 + X0) * 64;
    const _Float16* wbat  = wt + (size_t)b * 36864 + (size_t)(ot * 32 + px) * 16 + jj * 8;

    int offkw[3];
    #pragma unroll
    for (int kw = 0; kw < 3; ++kw) {
        int c = (px + kw) * 2 + jj;
        offkw[kw] = (c ^ ((c >> 3) & 7)) * 16;
    }
    const int Lb = rg * 4;

    #define STAGEQ(ICQ, BUF) do {                                                       \
        _Pragma("unroll")                                                               \
        for (int it = 0; it < 3; ++it) {                                                \
            int d  = it * 512 + tid;                                                    \
            int dc = d < 1296 ? d : 1295;                                               \
            int row = (int)((unsigned)dc / 72u);                                        \
            int c   = dc - row * 72;                                                    \
            int cs  = c ^ ((c >> 3) & 7);                                               \
            const _Float16* src = xbase + (size_t)row * 8320 + (cs >> 1) * 64           \
                                + (ICQ) * 16 + (cs & 1) * 8;                            \
            __builtin_amdgcn_global_load_lds(                                           \
                (const __attribute__((address_space(1))) void*)src,                     \
                (__attribute__((address_space(3))) void*)((__attribute__((address_space(3))) char*)xs + (BUF) * 24576 + (it * 512 + (tid & ~63)) * 16), \
                16, 0, 0);                                                              \
        } } while (0)

    STAGEQ(0, 0);
    half8 A[2][9];
    #pragma unroll
    for (int t = 0; t < 9; ++t) A[0][t] = *(const half8*)(wbat + t * 1024);

    f32x16 acc[4];
    #pragma unroll
    for (int r = 0; r < 4; ++r) acc[r] = (f32x16){};

    #pragma unroll
    for (int icq = 0; icq < 4; ++icq) {
        const int cur = icq & 1;
        if (icq < 3) {
            STAGEQ(icq + 1, cur ^ 1);
            asm volatile("s_waitcnt vmcnt(3)" ::: "memory");
        } else {
            asm volatile("s_waitcnt vmcnt(0)" ::: "memory");
        }
        __builtin_amdgcn_sched_barrier(0);
        __builtin_amdgcn_s_barrier();
        __builtin_amdgcn_sched_barrier(0);

        if (icq < 3) {
            #pragma unroll
            for (int t = 0; t < 9; ++t)
                A[cur ^ 1][t] = *(const half8*)(wbat + ((icq + 1) * 9 + t) * 1024);
        }

        const char* bufb = (const char*)xs + cur * 24576;
        #pragma unroll
        for (int kw = 0; kw < 3; ++kw) {
            half8 Bf[6];
            #pragma unroll
            for (int iy = 0; iy < 6; ++iy)
                Bf[iy] = *(const half8*)(bufb + (Lb + iy) * 1152 + offkw[kw]);
            #pragma unroll
            for (int iy = 0; iy < 6; ++iy) {
                #pragma unroll
                for (int kh = 0; kh < 3; ++kh) {
                    const int r = iy - kh;
                    if (r >= 0 && r < 4)
                        acc[r] = __builtin_amdgcn_mfma_f32_32x32x16_f16(A[cur][kh * 3 + kw], Bf[iy], acc[r], 0, 0, 0);
                }
            }
        }
        asm volatile("s_waitcnt lgkmcnt(0)" ::: "memory");
        __builtin_amdgcn_sched_barrier(0);
        __builtin_amdgcn_s_barrier();
        __builtin_amdgcn_sched_barrier(0);
    }
    #undef STAGEQ

    const float* bb = bias + b * 64;
    #pragma unroll
    for (int r = 0; r < 4; ++r) {
        const int yo = Y0g + Lb + r;
        float* ob = out + (((size_t)(b * 64 + ot * 32)) * 128 + yo) * 128 + X0 + px;
        #pragma unroll
        for (int reg = 0; reg < 16; ++reg) {
            const int ocl = (reg & 3) + 8 * (reg >> 2) + 4 * jj;
            ob[(size_t)ocl * 16384] = acc[r][reg] + bb[ot * 32 + ocl];
        }
    }
}

// ===================== FALLBACK (fp32 direct, R1) =====================
__global__ __launch_bounds__(256) void cond_gemm(const float* __restrict__ cond,
                                                 const float* __restrict__ Wc,
                                                 const float* __restrict__ bc,
                                                 float* __restrict__ wb) {
    __shared__ float condl[B_][CONDC + 1];
    __shared__ float Wl[16][CONDC + 1];
    const int tid = threadIdx.x;
    const int p0 = blockIdx.x * 16;
    for (int i = tid; i < B_ * CONDC; i += 256) condl[i >> 8][i & 255] = cond[i];
    for (int i = tid; i < 16 * CONDC; i += 256) {
        int pl = i >> 8, k = i & 255;
        Wl[pl][k] = Wc[(p0 + pl) * CONDC + k];
    }
    __syncthreads();
    const int pl = tid >> 4;
    const int b  = tid & 15;
    float acc = bc[p0 + pl];
    #pragma unroll 8
    for (int k = 0; k < CONDC; ++k) acc += Wl[pl][k] * condl[b][k];
    wb[b * NPARAM + p0 + pl] = tanhf(acc) * 5.0f;
}

#define TS  32
#define OG  8
#define ICC 8
__global__ __launch_bounds__(256) void conv_kernel(const float* __restrict__ x,
                                                   const float* __restrict__ wb,
                                                   float* __restrict__ out) {
    __shared__ float fxs[ICC][TS + 2][TS + 2];
    __shared__ float ws[OG][ICC][9];
    const int tid = threadIdx.x;
    const int b   = blockIdx.z;
    const int ocg = blockIdx.y * OG;
    const int tx0 = (blockIdx.x & 3) * TS;
    const int ty0 = (blockIdx.x >> 2) * TS;
    const int px  = (tid & 15) * 2;
    const int py  = (tid >> 4) * 2;
    float acc[OG][4];
    #pragma unroll
    for (int o = 0; o < OG; ++o)
        #pragma unroll
        for (int q = 0; q < 4; ++q) acc[o][q] = 0.0f;
    const float* wbase = wb + b * NPARAM;
    for (int ic0 = 0; ic0 < ICn; ic0 += ICC) {
        for (int i = tid; i < ICC * (TS + 2) * (TS + 2); i += 256) {
            int icl = i / ((TS + 2) * (TS + 2));
            int rem = i % ((TS + 2) * (TS + 2));
            int yy = rem / (TS + 2), xx = rem % (TS + 2);
            int gy = ty0 - 1 + yy, gx = tx0 - 1 + xx;
            float v = 0.0f;
            if (gy >= 0 && gy < Hn && gx >= 0 && gx < Wn)
                v = x[((b * ICn + ic0 + icl) * Hn + gy) * Wn + gx];
            fxs[icl][yy][xx] = v;
        }
        for (int i = tid; i < OG * ICC * 9; i += 256) {
            int o = i / (ICC * 9), rem = i % (ICC * 9);
            int icl = rem / 9, k = rem % 9;
            ws[o][icl][k] = wbase[((ocg + o) * ICn + ic0 + icl) * 9 + k];
        }
        __syncthreads();
        #pragma unroll
        for (int icl = 0; icl < ICC; ++icl) {
            float xv[4][4];
            #pragma unroll
            for (int dy = 0; dy < 4; ++dy)
                #pragma unroll
                for (int dx = 0; dx < 4; ++dx) xv[dy][dx] = fxs[icl][py + dy][px + dx];
            #pragma unroll
            for (int o = 0; o < OG; ++o)
                #pragma unroll
                for (int kh = 0; kh < 3; ++kh)
                    #pragma unroll
                    for (int kw = 0; kw < 3; ++kw) {
                        float wv = ws[o][icl][kh * 3 + kw];
                        acc[o][0] += xv[kh][kw] * wv;
                        acc[o][1] += xv[kh][kw + 1] * wv;
                        acc[o][2] += xv[kh + 1][kw] * wv;
                        acc[o][3] += xv[kh + 1][kw + 1] * wv;
                    }
        }
        __syncthreads();
    }
    #pragma unroll
    for (int o = 0; o < OG; ++o) {
        float bias = wbase[NW + ocg + o];
        int oc = ocg + o;
        float* obase = out + ((size_t)(b * OCn + oc) * Hn + (ty0 + py)) * Wn + tx0 + px;
        obase[0] = acc[o][0] + bias;
        obase[1] = acc[o][1] + bias;
        obase[Wn] = acc[o][2] + bias;
        obase[Wn + 1] = acc[o][3] + bias;
    }
}

// ===================== LAUNCH =====================
extern "C" void kernel_launch(void* const* d_in, const int* in_sizes, int n_in,
                              void* d_out, int out_size, void* d_ws, size_t ws_size,
                              hipStream_t stream) {
    const float* x    = (const float*)d_in[0];
    const float* cond = (const float*)d_in[1];
    const float* Wc   = (const float*)d_in[2];
    const float* bc   = (const float*)d_in[3];
    float* out = (float*)d_out;

    const size_t WT_BYTES = (size_t)B_ * 9 * 64 * 64 * 2;            // 1179648
    const size_t BIAS_OFF = WT_BYTES;
    const size_t XT_OFF   = 1183744;                                  // 256-aligned
    const size_t XT_BYTES = (size_t)B_ * 130 * 130 * 64 * 2 + 32768;  // + stage-overread pad
    const size_t NEED     = XT_OFF + XT_BYTES;

    if (ws_size >= NEED) {
        _Float16* wt   = (_Float16*)d_ws;
        float*    bias = (float*)((char*)d_ws + BIAS_OFF);
        _Float16* xt   = (_Float16*)((char*)d_ws + XT_OFF);
        transpose_k<<<dim3(2048 + 32), 256, 0, stream>>>(x, xt);
        gemm_k<<<dim3(577), 256, 0, stream>>>(cond, Wc, bc, wt, bias);
        conv_v4<<<dim3(4, 8, 16), 512, 0, stream>>>(xt, wt, bias, out);
    } else {
        float* wbuf = (float*)d_ws;
        cond_gemm<<<dim3(NPARAM / 16), 256, 0, stream>>>(cond, Wc, bc, wbuf);
        conv_kernel<<<dim3(16, OCn / OG, B_), 256, 0, stream>>>(x, wbuf, out);
    }
}

// Round 8
// 62.774 us; speedup vs baseline: 1.1141x; 1.1141x over previous
//
#include <hip/hip_runtime.h>
#include <math.h>
#include <stdint.h>

#define B_    16
#define CONDC 256
#define ICn   64
#define OCn   64
#define Hn    128
#define Wn    128
#define NW    36864
#define NPARAM 36928

typedef _Float16 half8 __attribute__((ext_vector_type(8)));
typedef _Float16 half4 __attribute__((ext_vector_type(4)));
typedef float f32x4 __attribute__((ext_vector_type(4)));
typedef float f32x16 __attribute__((ext_vector_type(16)));

__device__ inline unsigned pk2(float a, float b) {
    union { _Float16 h[2]; unsigned u; } q;
    q.h[0] = (_Float16)a; q.h[1] = (_Float16)b;
    return q.u;
}

// ===================== TRANSPOSE: x[b][ic][y][:] f32 -> xt[b][y+1][x+1][ic] f16 =====================
__global__ void transpose_k(const float* __restrict__ x, _Float16* __restrict__ xt) {
    __shared__ unsigned ls[4160];              // [32 icp][130] u32
    const int tid = threadIdx.x;
    const int bx  = blockIdx.x;

    if (bx < 2048) {
        const int b = bx >> 7, y = bx & 127;
        const float* xrow = x + (size_t)b * 1048576 + (size_t)y * 128;

        float4 va[4], vb[4];                   // all 8 loads issued, pinned
        #pragma unroll
        for (int t = 0; t < 4; ++t) {
            int u = t * 256 + tid;
            int icp = u >> 5, xg = u & 31;
            const float* r0 = xrow + (size_t)(2 * icp) * 16384;
            va[t] = *((const float4*)r0 + xg);
            vb[t] = *((const float4*)(r0 + 16384) + xg);
        }
        __builtin_amdgcn_sched_barrier(0);

        #pragma unroll
        for (int t = 0; t < 4; ++t) {
            int u = t * 256 + tid;
            int icp = u >> 5, xg = u & 31;
            unsigned* dst = ls + icp * 130 + 4 * xg;
            *(uint2*)(dst)     = make_uint2(pk2(va[t].x, vb[t].x), pk2(va[t].y, vb[t].y));
            *(uint2*)(dst + 2) = make_uint2(pk2(va[t].z, vb[t].z), pk2(va[t].w, vb[t].w));
        }
        __syncthreads();

        _Float16* rowhalf = xt + (size_t)(b * 130 + y + 1) * 8320;
        #pragma unroll
        for (int t = 0; t < 5; ++t) {
            int u = t * 256 + tid;
            if (u < 1040) {
                int xp = u >> 3, g = u & 7;
                uint4 val = make_uint4(0u, 0u, 0u, 0u);
                if (xp > 0 && xp < 129) {
                    int xx = xp - 1;
                    val.x = ls[(4 * g + 0) * 130 + xx];
                    val.y = ls[(4 * g + 1) * 130 + xx];
                    val.z = ls[(4 * g + 2) * 130 + xx];
                    val.w = ls[(4 * g + 3) * 130 + xx];
                }
                *(uint4*)(rowhalf + (size_t)u * 8) = val;
            }
        }
    } else {
        const int q = bx - 2048;
        const int b = q >> 1, yp = (q & 1) ? 129 : 0;
        _Float16* rowhalf = xt + (size_t)(b * 130 + yp) * 8320;
        uint4 z = make_uint4(0u, 0u, 0u, 0u);
        for (int u = tid; u < 1040; u += 256)
            *(uint4*)(rowhalf + (size_t)u * 8) = z;
    }
}

// ===================== COND-GEMM: wt[b][icq][tap][oc][ic16] f16 + bias =====================
__global__ __launch_bounds__(256, 4) void gemm_k(const float* __restrict__ cond,
                                                 const float* __restrict__ Wc,
                                                 const float* __restrict__ bc,
                                                 _Float16* __restrict__ wt,
                                                 float* __restrict__ bias) {
    __shared__ _Float16 wl[64 * 280];          // 35840 B
    const int tid = threadIdx.x;
    const int pbase = blockIdx.x * 64;

    float4 v[16];
    #pragma unroll
    for (int t = 0; t < 16; ++t) {
        int u = t * 256 + tid;
        int pl = u >> 6, kg = u & 63;
        v[t] = *((const float4*)(Wc + (size_t)(pbase + pl) * 256) + kg);
    }
    __builtin_amdgcn_sched_barrier(0);

    #pragma unroll
    for (int t = 0; t < 16; ++t) {
        int u = t * 256 + tid;
        int pl = u >> 6, kg = u & 63;
        half4 h = { (_Float16)v[t].x, (_Float16)v[t].y, (_Float16)v[t].z, (_Float16)v[t].w };
        *(half4*)(wl + pl * 280 + kg * 4) = h;
    }
    __syncthreads();

    const int w = tid >> 6, l = tid & 63, n = l & 15, r4 = l >> 4;
    const _Float16* arow = wl + (w * 16 + n) * 280 + r4 * 8;
    const float*    crow = cond + n * 256 + r4 * 8;
    f32x4 acc = (f32x4){0.f, 0.f, 0.f, 0.f};
    #pragma unroll
    for (int kk = 0; kk < 8; ++kk) {
        half8 av = *(const half8*)(arow + kk * 32);
        float4 u0 = *(const float4*)(crow + kk * 32);
        float4 u1 = *(const float4*)(crow + kk * 32 + 4);
        half8 bv;
        bv[0] = (_Float16)u0.x; bv[1] = (_Float16)u0.y; bv[2] = (_Float16)u0.z; bv[3] = (_Float16)u0.w;
        bv[4] = (_Float16)u1.x; bv[5] = (_Float16)u1.y; bv[6] = (_Float16)u1.z; bv[7] = (_Float16)u1.w;
        acc = __builtin_amdgcn_mfma_f32_16x16x32_f16(av, bv, acc, 0, 0, 0);
    }
    #pragma unroll
    for (int j = 0; j < 4; ++j) {
        int p = pbase + w * 16 + r4 * 4 + j;
        float vv = tanhf(acc[j] + bc[p]) * 5.0f;
        if (p < NW) {
            int oc = p / 576, rem = p - oc * 576;
            int ic = rem / 9,  t  = rem - ic * 9;
            int icq = ic >> 4, icl = ic & 15;
            wt[((((size_t)n * 4 + icq) * 9 + t) * 64 + oc) * 16 + icl] = (_Float16)vv;
        } else {
            bias[n * 64 + (p - NW)] = vv;
        }
    }
}

// ===================== CONV v5: 256-thr blocks, 8-row tiles, depth-2/3 pipeline, exact vmcnt =====================
// 1024 blocks (XCD-swizzled). Block: 32px x 8rows x 64oc; 4 waves = ot(2) x rg(2), wave = 32oc x 32px x 4rows.
// K = 4 ic16-slices x 9 taps; B-slices triple-buffered in LDS [10 rows][36 px][16 ic], 12288 B each.
__global__ __launch_bounds__(256, 3) void conv_v5(const _Float16* __restrict__ xt,
                                                  const _Float16* __restrict__ wt,
                                                  const float* __restrict__ bias,
                                                  float* __restrict__ out) {
    __shared__ _Float16 xs[3 * 6144];          // 3 x 12288 B
    const int tid = threadIdx.x;
    const int l   = tid & 63;
    const int w   = tid >> 6;
    const int px  = l & 31;
    const int jj  = l >> 5;
    const int ot  = w & 1;
    const int rg  = w >> 1;

    // bijective XCD swizzle: 1024 % 8 == 0
    const int sw = (blockIdx.x & 7) * 128 + (blockIdx.x >> 3);
    const int Xt = sw & 3, Yt = (sw >> 2) & 15, b = sw >> 6;
    const int X0  = Xt * 32;
    const int Y0g = Yt * 8;                    // padded top row of block's input window

    const _Float16* xbase = xt + ((size_t)(b * 130 + Y0g) * 130 + X0) * 64;
    const _Float16* wbat  = wt + (size_t)b * 36864 + (size_t)(ot * 32 + px) * 16 + jj * 8;

    int offkw[3];
    #pragma unroll
    for (int kw = 0; kw < 3; ++kw) {
        int c = (px + kw) * 2 + jj;
        offkw[kw] = (c ^ ((c >> 3) & 7)) * 16;
    }
    const int Lb = rg * 4;

    // stage slice ICQ (10 rows x 72 chunks = 720; 3x256 with harmless tail overrun into pad)
    #define STAGEQ(ICQ, BUF) do {                                                       \
        _Pragma("unroll")                                                               \
        for (int it = 0; it < 3; ++it) {                                                \
            int d   = it * 256 + tid;                                                   \
            int row = (int)((unsigned)d / 72u);                                         \
            int c   = d - row * 72;                                                     \
            int cs  = c ^ ((c >> 3) & 7);                                               \
            const _Float16* src = xbase + (size_t)row * 8320 + (cs >> 1) * 64           \
                                + (ICQ) * 16 + (cs & 1) * 8;                            \
            __builtin_amdgcn_global_load_lds(                                           \
                (const __attribute__((address_space(1))) void*)src,                     \
                (__attribute__((address_space(3))) void*)((__attribute__((address_space(3))) char*)xs + (BUF) * 12288 + (it * 256 + (tid & ~63)) * 16), \
                16, 0, 0);                                                              \
        } } while (0)

    #define LOADA(AIDX, ICQ) do {                                                       \
        _Pragma("unroll")                                                               \
        for (int t = 0; t < 9; ++t)                                                     \
            A[AIDX][t] = *(const half8*)(wbat + (size_t)((ICQ) * 9 + t) * 1024);        \
        } while (0)

    #define COMPUTE(AIDX, BUF) do {                                                     \
        const char* bufb = (const char*)xs + (BUF) * 12288;                             \
        _Pragma("unroll")                                                               \
        for (int kw = 0; kw < 3; ++kw) {                                                \
            half8 Bf[6];                                                                \
            _Pragma("unroll")                                                           \
            for (int iy = 0; iy < 6; ++iy)                                              \
                Bf[iy] = *(const half8*)(bufb + (Lb + iy) * 1152 + offkw[kw]);          \
            _Pragma("unroll")                                                           \
            for (int iy = 0; iy < 6; ++iy) {                                            \
                _Pragma("unroll")                                                       \
                for (int kh = 0; kh < 3; ++kh) {                                        \
                    const int r = iy - kh;                                              \
                    if (r >= 0 && r < 4)                                                \
                        acc[r] = __builtin_amdgcn_mfma_f32_32x32x16_f16(A[AIDX][kh * 3 + kw], Bf[iy], acc[r], 0, 0, 0); \
                } } } } while (0)

    half8 A[2][9];
    f32x16 acc[4];
    #pragma unroll
    for (int r = 0; r < 4; ++r) acc[r] = (f32x16){};

    // ---- prologue: A0(9) S0(3) S1(3) S2(3) ----
    LOADA(0, 0);
    __builtin_amdgcn_sched_barrier(0);
    STAGEQ(0, 0); STAGEQ(1, 1); STAGEQ(2, 2);
    __builtin_amdgcn_sched_barrier(0);

    // ---- i0: A1(9); drain A0+S0 -> vmcnt(15) ----
    LOADA(1, 1);
    __builtin_amdgcn_sched_barrier(0);
    asm volatile("s_waitcnt vmcnt(15)" ::: "memory");
    __builtin_amdgcn_sched_barrier(0);
    __builtin_amdgcn_s_barrier();
    __builtin_amdgcn_sched_barrier(0);
    COMPUTE(0, 0);
    asm volatile("s_waitcnt lgkmcnt(0)" ::: "memory");
    __builtin_amdgcn_sched_barrier(0);
    __builtin_amdgcn_s_barrier();              // buf0 free for re-stage
    __builtin_amdgcn_sched_barrier(0);
    STAGEQ(3, 0);
    __builtin_amdgcn_sched_barrier(0);

    // ---- i1: A2(9); drain S1+A1 (newer: S3+A2=12) ----
    LOADA(0, 2);
    __builtin_amdgcn_sched_barrier(0);
    asm volatile("s_waitcnt vmcnt(12)" ::: "memory");
    __builtin_amdgcn_sched_barrier(0);
    __builtin_amdgcn_s_barrier();
    __builtin_amdgcn_sched_barrier(0);
    COMPUTE(1, 1);

    // ---- i2: A3(9); drain S2+A2 (newer: A3=9) ----
    LOADA(1, 3);
    __builtin_amdgcn_sched_barrier(0);
    asm volatile("s_waitcnt vmcnt(9)" ::: "memory");
    __builtin_amdgcn_sched_barrier(0);
    __builtin_amdgcn_s_barrier();
    __builtin_amdgcn_sched_barrier(0);
    COMPUTE(0, 2);

    // ---- i3: drain all ----
    asm volatile("s_waitcnt vmcnt(0)" ::: "memory");
    __builtin_amdgcn_sched_barrier(0);
    __builtin_amdgcn_s_barrier();
    __builtin_amdgcn_sched_barrier(0);
    COMPUTE(1, 0);

    #undef STAGEQ
    #undef LOADA
    #undef COMPUTE

    // ---- epilogue: D col = lane&31 = px, oc-within-32 = (reg&3)+8*(reg>>2)+4*jj ----
    const float* bb = bias + b * 64;
    #pragma unroll
    for (int r = 0; r < 4; ++r) {
        const int yo = Y0g + Lb + r;
        float* ob = out + (((size_t)(b * 64 + ot * 32)) * 128 + yo) * 128 + X0 + px;
        #pragma unroll
        for (int reg = 0; reg < 16; ++reg) {
            const int ocl = (reg & 3) + 8 * (reg >> 2) + 4 * jj;
            ob[(size_t)ocl * 16384] = acc[r][reg] + bb[ot * 32 + ocl];
        }
    }
}

// ===================== FALLBACK (fp32 direct, R1) =====================
__global__ __launch_bounds__(256) void cond_gemm(const float* __restrict__ cond,
                                                 const float* __restrict__ Wc,
                                                 const float* __restrict__ bc,
                                                 float* __restrict__ wb) {
    __shared__ float condl[B_][CONDC + 1];
    __shared__ float Wl[16][CONDC + 1];
    const int tid = threadIdx.x;
    const int p0 = blockIdx.x * 16;
    for (int i = tid; i < B_ * CONDC; i += 256) condl[i >> 8][i & 255] = cond[i];
    for (int i = tid; i < 16 * CONDC; i += 256) {
        int pl = i >> 8, k = i & 255;
        Wl[pl][k] = Wc[(p0 + pl) * CONDC + k];
    }
    __syncthreads();
    const int pl = tid >> 4;
    const int b  = tid & 15;
    float acc = bc[p0 + pl];
    #pragma unroll 8
    for (int k = 0; k < CONDC; ++k) acc += Wl[pl][k] * condl[b][k];
    wb[b * NPARAM + p0 + pl] = tanhf(acc) * 5.0f;
}

#define TS  32
#define OG  8
#define ICC 8
__global__ __launch_bounds__(256) void conv_kernel(const float* __restrict__ x,
                                                   const float* __restrict__ wb,
                                                   float* __restrict__ out) {
    __shared__ float fxs[ICC][TS + 2][TS + 2];
    __shared__ float ws[OG][ICC][9];
    const int tid = threadIdx.x;
    const int b   = blockIdx.z;
    const int ocg = blockIdx.y * OG;
    const int tx0 = (blockIdx.x & 3) * TS;
    const int ty0 = (blockIdx.x >> 2) * TS;
    const int px  = (tid & 15) * 2;
    const int py  = (tid >> 4) * 2;
    float acc[OG][4];
    #pragma unroll
    for (int o = 0; o < OG; ++o)
        #pragma unroll
        for (int q = 0; q < 4; ++q) acc[o][q] = 0.0f;
    const float* wbase = wb + b * NPARAM;
    for (int ic0 = 0; ic0 < ICn; ic0 += ICC) {
        for (int i = tid; i < ICC * (TS + 2) * (TS + 2); i += 256) {
            int icl = i / ((TS + 2) * (TS + 2));
            int rem = i % ((TS + 2) * (TS + 2));
            int yy = rem / (TS + 2), xx = rem % (TS + 2);
            int gy = ty0 - 1 + yy, gx = tx0 - 1 + xx;
            float v = 0.0f;
            if (gy >= 0 && gy < Hn && gx >= 0 && gx < Wn)
                v = x[((b * ICn + ic0 + icl) * Hn + gy) * Wn + gx];
            fxs[icl][yy][xx] = v;
        }
        for (int i = tid; i < OG * ICC * 9; i += 256) {
            int o = i / (ICC * 9), rem = i % (ICC * 9);
            int icl = rem / 9, k = rem % 9;
            ws[o][icl][k] = wbase[((ocg + o) * ICn + ic0 + icl) * 9 + k];
        }
        __syncthreads();
        #pragma unroll
        for (int icl = 0; icl < ICC; ++icl) {
            float xv[4][4];
            #pragma unroll
            for (int dy = 0; dy < 4; ++dy)
                #pragma unroll
                for (int dx = 0; dx < 4; ++dx) xv[dy][dx] = fxs[icl][py + dy][px + dx];
            #pragma unroll
            for (int o = 0; o < OG; ++o)
                #pragma unroll
                for (int kh = 0; kh < 3; ++kh)
                    #pragma unroll
                    for (int kw = 0; kw < 3; ++kw) {
                        float wv = ws[o][icl][kh * 3 + kw];
                        acc[o][0] += xv[kh][kw] * wv;
                        acc[o][1] += xv[kh][kw + 1] * wv;
                        acc[o][2] += xv[kh + 1][kw] * wv;
                        acc[o][3] += xv[kh + 1][kw + 1] * wv;
                    }
        }
        __syncthreads();
    }
    #pragma unroll
    for (int o = 0; o < OG; ++o) {
        float bias = wbase[NW + ocg + o];
        int oc = ocg + o;
        float* obase = out + ((size_t)(b * OCn + oc) * Hn + (ty0 + py)) * Wn + tx0 + px;
        obase[0] = acc[o][0] + bias;
        obase[1] = acc[o][1] + bias;
        obase[Wn] = acc[o][2] + bias;
        obase[Wn + 1] = acc[o][3] + bias;
    }
}

// ===================== LAUNCH =====================
extern "C" void kernel_launch(void* const* d_in, const int* in_sizes, int n_in,
                              void* d_out, int out_size, void* d_ws, size_t ws_size,
                              hipStream_t stream) {
    const float* x    = (const float*)d_in[0];
    const float* cond = (const float*)d_in[1];
    const float* Wc   = (const float*)d_in[2];
    const float* bc   = (const float*)d_in[3];
    float* out = (float*)d_out;

    const size_t WT_BYTES = (size_t)B_ * 9 * 64 * 64 * 2;            // 1179648
    const size_t BIAS_OFF = WT_BYTES;
    const size_t XT_OFF   = 1183744;                                  // 256-aligned
    const size_t XT_BYTES = (size_t)B_ * 130 * 130 * 64 * 2 + 32768;  // + stage-overread pad
    const size_t NEED     = XT_OFF + XT_BYTES;

    if (ws_size >= NEED) {
        _Float16* wt   = (_Float16*)d_ws;
        float*    bias = (float*)((char*)d_ws + BIAS_OFF);
        _Float16* xt   = (_Float16*)((char*)d_ws + XT_OFF);
        transpose_k<<<dim3(2048 + 32), 256, 0, stream>>>(x, xt);
        gemm_k<<<dim3(577), 256, 0, stream>>>(cond, Wc, bc, wt, bias);
        conv_v5<<<dim3(1024), 256, 0, stream>>>(xt, wt, bias, out);
    } else {
        float* wbuf = (float*)d_ws;
        cond_gemm<<<dim3(NPARAM / 16), 256, 0, stream>>>(cond, Wc, bc, wbuf);
        conv_kernel<<<dim3(16, OCn / OG, B_), 256, 0, stream>>>(x, wbuf, out);
    }
}